// Round 22
// baseline (205.063 us; speedup 1.0000x reference)
//
#include <hip/hip_runtime.h>
#include <math.h>

#define CH 192
#define HW 4096
#define NB 16
#define NELEM (NB*CH*HW)
#define HIDN 768

typedef __bf16 bf16x8 __attribute__((ext_vector_type(8)));
typedef float  f32x4  __attribute__((ext_vector_type(4)));
typedef unsigned uint4v __attribute__((ext_vector_type(4)));

__device__ __forceinline__ float gelu_f(float v){
    return v / (1.0f + __expf(-1.702f*v));
}
__device__ __forceinline__ float sigmoid_f(float v){
    return 1.0f / (1.0f + __expf(-v));
}
__device__ __forceinline__ unsigned pack2bf(float a, float b){
    union { __bf16 h[2]; unsigned u; } v;
    v.h[0] = (__bf16)a; v.h[1] = (__bf16)b; return v.u;
}

// ---------------- K0: f32 -> bf16 weight conversion, all four matrices in one launch
__global__ __launch_bounds__(256) void k_cvt_all(
    const float* __restrict__ a0, const float* __restrict__ a1,
    const float* __restrict__ a2, const float* __restrict__ a3,
    __bf16* __restrict__ o)
{
    const int n0 = 2*CH*CH, n1 = CH*CH, n2 = HIDN*CH, n3 = CH*HIDN;
    int i = blockIdx.x*256 + threadIdx.x;
    if (i < n0) o[i] = (__bf16)a0[i];
    else if (i < n0+n1) o[i] = (__bf16)a1[i-n0];
    else if (i < n0+n1+n2) o[i] = (__bf16)a2[i-n0-n1];
    else if (i < n0+n1+n2+n3) o[i] = (__bf16)a3[i-n0-n1-n2];
}

// ---------------- K1: LN1 + in_proj (192->384) via bf16 MFMA -> bf16 proj / sigmoid gate
__global__ __launch_bounds__(256, 4) void k_ln_inproj(
    const float* __restrict__ x, const float* __restrict__ lw, const float* __restrict__ lb,
    const __bf16* __restrict__ Wb, const float* __restrict__ bias,
    __bf16* __restrict__ proj, __bf16* __restrict__ gate)
{
    __shared__ __align__(16) unsigned char smem[33792];
    __bf16* h2s = (__bf16*)smem;                       // 192*64 frag-linear (24576B)
    float* redS = (float*)(smem + 24576);              // LN scratch (dead post-MFMA)
    float* redQ = (float*)(smem + 25600);
    float* mS   = (float*)(smem + 26624);
    float* rS   = (float*)(smem + 26880);
    __bf16* outb = (__bf16*)(smem + 24576);            // 64ch x 72 bounce (9216B)

    int tid = threadIdx.x;
    int lane = tid & 63;
    int w = tid >> 6;
    int lo = lane & 15, hi = lane >> 4;
    int bid = blockIdx.x;
    int b = bid >> 6;
    int p0 = (bid & 63) << 6;
    const float* xb = x + (size_t)b*CH*HW + p0;
    int px = lane;

    float xv[48];
    float s = 0.f, s2 = 0.f;
    #pragma unroll
    for (int k = 0; k < 48; ++k){
        float v = xb[(size_t)(48*w + k)*HW + px];
        xv[k] = v; s += v; s2 += v*v;
    }
    redS[tid] = s; redQ[tid] = s2;
    __syncthreads();
    if (tid < 64){
        float S = redS[tid]+redS[tid+64]+redS[tid+128]+redS[tid+192];
        float Q = redQ[tid]+redQ[tid+64]+redQ[tid+128]+redQ[tid+192];
        float mean = S * (1.f/192.f);
        float var  = Q * (1.f/192.f) - mean*mean;
        mS[tid] = mean;
        rS[tid] = rsqrtf(var + 1e-6f);
    }
    __syncthreads();
    {
        float mean = mS[px], rstd = rS[px];
        #pragma unroll
        for (int m = 0; m < 6; ++m){
            int c8 = 48*w + 8*m;
            int ks = c8 >> 5, hh = (c8 >> 3) & 3;
            bf16x8 pk;
            #pragma unroll
            for (int j = 0; j < 8; ++j){
                int c = c8 + j;
                pk[j] = (__bf16)((xv[8*m + j] - mean) * rstd * lw[c] + lb[c]);
            }
            *(bf16x8*)(h2s + (((px>>4)*6 + ks)*64 + hh*16 + (px & 15))*8) = pk;
        }
    }
    __syncthreads();

    #pragma unroll
    for (int g = 0; g < 2; ++g){
        f32x4 acc[3][4];
        #pragma unroll
        for (int nt = 0; nt < 3; ++nt)
            #pragma unroll
            for (int pt = 0; pt < 4; ++pt)
                acc[nt][pt] = (f32x4){0.f,0.f,0.f,0.f};
        #pragma unroll
        for (int ks = 0; ks < 6; ++ks){
            bf16x8 a[4];
            #pragma unroll
            for (int pt = 0; pt < 4; ++pt)
                a[pt] = *(const bf16x8*)(h2s + ((pt*6 + ks)*64 + lane)*8);
            #pragma unroll
            for (int nt = 0; nt < 3; ++nt){
                bf16x8 bf = *(const bf16x8*)
                    (Wb + (size_t)(g*192 + w*48 + nt*16 + lo)*CH + ks*32 + hi*8);
                #pragma unroll
                for (int pt = 0; pt < 4; ++pt)
                    acc[nt][pt] = __builtin_amdgcn_mfma_f32_16x16x32_bf16(
                        a[pt], bf, acc[nt][pt], 0, 0, 0);
            }
        }
        __bf16* dst = (g == 0) ? proj : gate;
        #pragma unroll
        for (int nt = 0; nt < 3; ++nt){
            __syncthreads();
            int oc = w*48 + nt*16 + lo;
            float bv = bias[g*CH + oc];
            int cc = w*16 + lo;
            #pragma unroll
            for (int pt = 0; pt < 4; ++pt)
                #pragma unroll
                for (int r = 0; r < 4; ++r){
                    float v = acc[nt][pt][r] + bv;
                    if (g == 1) v = sigmoid_f(v);
                    outb[cc*72 + pt*16 + hi*4 + r] = (__bf16)v;
                }
            __syncthreads();
            #pragma unroll
            for (int k = 0; k < 2; ++k){
                int i = tid + k*256;
                int c2 = i >> 3, vg = i & 7;
                int c = (c2 >> 4)*48 + nt*16 + (c2 & 15);
                bf16x8 o8 = *(const bf16x8*)(outb + c2*72 + vg*8);
                *(bf16x8*)(dst + (size_t)(b*CH + c)*HW + p0 + vg*8) = o8;
            }
        }
        __syncthreads();
    }
}

// ---------------- K2: fused spatial: dwconv3 + 4-dir scans + local conv3 + gate + BN partials
__global__ __launch_bounds__(256, 4) void k_spatial(
    const __bf16* __restrict__ proj, const __bf16* __restrict__ gate,
    const float* __restrict__ dwk, const float* __restrict__ lek,
    const float* __restrict__ dl, const float* __restrict__ ml, const float* __restrict__ il,
    __bf16* __restrict__ mixed, float* __restrict__ part)
{
    __shared__ float t[66*67];
    __shared__ __bf16 r[64*65];
    __shared__ __bf16 r2[64*65];
    __shared__ float rs[256], rq[256];
    int tid = threadIdx.x;
    int lane = tid & 63;
    int w = tid >> 6;
    int bc = blockIdx.x;
    int c = bc % CH;
    const __bf16* pp = proj + (size_t)bc*HW;

    for (int i = tid; i < 66*67; i += 256) t[i] = 0.f;
    float d[4], e[4], m[4];
    {
        float lg[4], mx = -1e30f;
        #pragma unroll
        for (int k = 0; k < 4; ++k){ lg[k] = ml[k*CH + c]; mx = fmaxf(mx, lg[k]); }
        float se = 0.f;
        #pragma unroll
        for (int k = 0; k < 4; ++k){ lg[k] = __expf(lg[k]-mx); se += lg[k]; }
        #pragma unroll
        for (int k = 0; k < 4; ++k){
            m[k] = lg[k] / se;
            float dd = sigmoid_f(dl[k*CH + c]);
            dd = fminf(fmaxf(dd, 0.05f), 0.995f);
            d[k] = dd;
            e[k] = (1.0f - dd) * (1.0f + tanhf(il[k*CH + c]));
        }
    }
    __syncthreads();
    #pragma unroll
    for (int k = 0; k < 2; ++k){
        int i = tid + k*256;
        int y = i >> 3, vg = i & 7;
        bf16x8 p8 = *(const bf16x8*)(pp + y*64 + vg*8);
        #pragma unroll
        for (int j = 0; j < 8; ++j)
            t[(y+1)*67 + vg*8 + j + 1] = (float)p8[j];
    }
    __syncthreads();
    float kk[9];
    #pragma unroll
    for (int j = 0; j < 9; ++j) kk[j] = dwk[c*9 + j];
    float dw[16];
    #pragma unroll
    for (int j = 0; j < 16; ++j){
        int i = tid + j*256;
        int y = i >> 6, xx = i & 63;
        float sv = 0.f;
        #pragma unroll
        for (int dy = 0; dy < 3; ++dy)
            #pragma unroll
            for (int dx = 0; dx < 3; ++dx)
                sv = fmaf(kk[dy*3+dx], t[(y+dy)*67 + xx + dx], sv);
        dw[j] = sv;
    }
    __syncthreads();
    #pragma unroll
    for (int j = 0; j < 16; ++j){
        int i = tid + j*256;
        t[((i>>6)+1)*67 + (i & 63) + 1] = dw[j];
    }
    __syncthreads();
    if (w == 0){
        int y = lane; float s = 0.f;
        for (int xx = 0; xx < 64; ++xx){
            s = fmaf(d[0], s, e[0]*t[(y+1)*67 + xx + 1]);
            r[y*65 + xx] = (__bf16)(m[0]*s);
        }
    } else if (w == 1){
        int xx = lane; float s = 0.f;
        for (int y = 0; y < 64; ++y){
            s = fmaf(d[2], s, e[2]*t[(y+1)*67 + xx + 1]);
            r2[y*65 + xx] = (__bf16)(m[2]*s);
        }
    }
    __syncthreads();
    if (w == 2){
        int y = lane; float s = 0.f;
        for (int xx = 63; xx >= 0; --xx){
            s = fmaf(d[1], s, e[1]*t[(y+1)*67 + xx + 1]);
            r[y*65 + xx] = (__bf16)((float)r[y*65 + xx] + m[1]*s);
        }
    } else if (w == 3){
        int xx = lane; float s = 0.f;
        for (int y = 63; y >= 0; --y){
            s = fmaf(d[3], s, e[3]*t[(y+1)*67 + xx + 1]);
            r2[y*65 + xx] = (__bf16)((float)r2[y*65 + xx] + m[3]*s);
        }
    }
    __syncthreads();
    float lk[9];
    #pragma unroll
    for (int j = 0; j < 9; ++j) lk[j] = lek[c*9 + j];
    const __bf16* gp = gate + (size_t)bc*HW;
    __bf16* mp = mixed + (size_t)bc*HW;
    float s1 = 0.f, s2 = 0.f;
    #pragma unroll
    for (int k = 0; k < 2; ++k){
        int i = tid + k*256;
        int y = i >> 3, vg = i & 7;
        bf16x8 g8 = *(const bf16x8*)(gp + y*64 + vg*8);
        bf16x8 m8;
        #pragma unroll
        for (int j = 0; j < 8; ++j){
            int xx = vg*8 + j;
            float sv = 0.f;
            #pragma unroll
            for (int dy = 0; dy < 3; ++dy)
                #pragma unroll
                for (int dx = 0; dx < 3; ++dx)
                    sv = fmaf(lk[dy*3+dx], t[(y+dy)*67 + xx + dx], sv);
            float mv = ((float)r[y*65 + xx] + (float)r2[y*65 + xx] + sv) * (float)g8[j];
            m8[j] = (__bf16)mv;
            s1 += mv; s2 += mv*mv;
        }
        *(bf16x8*)(mp + y*64 + vg*8) = m8;
    }
    rs[tid] = s1; rq[tid] = s2;
    __syncthreads();
    for (int off = 128; off > 0; off >>= 1){
        if (tid < off){ rs[tid] += rs[tid+off]; rq[tid] += rq[tid+off]; }
        __syncthreads();
    }
    if (tid == 0){ part[bc] = rs[0]; part[NB*CH + bc] = rq[0]; }
}

// ---------------- K3: FUSED tail. v2: early-issued mixed loads (before BN reduce)
// and early-issued x loads (after out_proj MFMA, before bounce barrier).
__global__ __launch_bounds__(256, 4) void k_tail2(
    const __bf16* __restrict__ mixed,
    const float* __restrict__ part, const float* __restrict__ bnw, const float* __restrict__ bnb,
    const __bf16* __restrict__ Wo, const float* __restrict__ biaso,
    const float* __restrict__ x,
    const float* __restrict__ lw, const float* __restrict__ lb,
    const __bf16* __restrict__ w1b, const float* __restrict__ b1,
    const __bf16* __restrict__ w2b, const float* __restrict__ b2,
    float* __restrict__ outp)
{
    __shared__ __align__(16) unsigned char smem[40960];
    __bf16* h2s = (__bf16*)smem;                    // 24576B act frags (persistent in MLP)
    __bf16* tt0 = (__bf16*)(smem + 24576);          // 8192B fc1-out frags, buffer 0
    __bf16* tt1 = (__bf16*)(smem + 32768);          // 8192B fc1-out frags, buffer 1
    __bf16* outb66 = (__bf16*)smem;                 // 192*66 bf16 oproj bounce (25344B)
    float* redS = (float*)(smem + 25600);           // LN scratch in tt region (tt dead)
    float* redQ = (float*)(smem + 26624);
    float* mS   = (float*)(smem + 27648);
    float* rS   = (float*)(smem + 27904);
    float* bnpl = (float*)(smem + 28160);           // 2*192 f32 BN scale/shift (1536B)
    float* outf = (float*)smem;                     // 96*68 f32 epilogue bounce (26112B)

    int tid = threadIdx.x;
    int lane = tid & 63;
    int w = tid >> 6;
    int lo = lane & 15, hi = lane >> 4;
    int bid = blockIdx.x;
    int b = bid >> 6;
    int p0 = (bid & 63) << 6;
    int px = lane;
    const __bf16* mb = mixed + (size_t)b*CH*HW + p0;

    // ---- P0a: issue mixed loads NOW (independent of BN reduce)
    bf16x8 mreg[6];
    #pragma unroll
    for (int k = 0; k < 6; ++k){
        int V = tid + k*256;
        int c = V >> 3, vg = V & 7;
        mreg[k] = *(const bf16x8*)(mb + (size_t)c*HW + vg*8);
    }

    // ---- P0b: BN finalize (redundant per block; part is L2-hot)
    if (tid < CH){
        float S = 0.f, Q = 0.f;
        #pragma unroll
        for (int bb2 = 0; bb2 < NB; ++bb2){
            S += part[bb2*CH + tid];
            Q += part[NB*CH + bb2*CH + tid];
        }
        float mean = S * (1.f/65536.f);
        float var  = Q * (1.f/65536.f) - mean*mean;
        float sc = bnw[tid] * rsqrtf(var + 1e-5f);
        bnpl[tid] = sc;
        bnpl[CH + tid] = bnb[tid] - mean * sc;
    }
    __syncthreads();

    // ---- P1: BN + GELU -> frag-linear bf16 (from registers)
    #pragma unroll
    for (int k = 0; k < 6; ++k){
        int V = tid + k*256;
        int c = V >> 3, vg = V & 7;
        int ks = c >> 5, hh = (c >> 3) & 3, j2 = c & 7;
        float sc_ = bnpl[c], sh_ = bnpl[CH + c];
        #pragma unroll
        for (int j = 0; j < 8; ++j){
            int p2 = vg*8 + j;
            float v = gelu_f(fmaf((float)mreg[k][j], sc_, sh_));
            h2s[((((p2>>4)*6 + ks) << 6) + hh*16 + (p2 & 15))*8 + j2] = (__bf16)v;
        }
    }
    __syncthreads();

    float xvr[48];
    // ---- P2: out_proj MFMA (then early-issue x loads before the bounce barrier)
    {
        f32x4 acc[3][4];
        #pragma unroll
        for (int nt = 0; nt < 3; ++nt)
            #pragma unroll
            for (int pt = 0; pt < 4; ++pt)
                acc[nt][pt] = (f32x4){0.f,0.f,0.f,0.f};
        #pragma unroll
        for (int ks = 0; ks < 6; ++ks){
            bf16x8 a[4];
            #pragma unroll
            for (int pt = 0; pt < 4; ++pt)
                a[pt] = *(const bf16x8*)(h2s + ((pt*6 + ks)*64 + lane)*8);
            #pragma unroll
            for (int nt = 0; nt < 3; ++nt){
                bf16x8 bf = *(const bf16x8*)
                    (Wo + (size_t)(w*48 + nt*16 + lo)*CH + ks*32 + hi*8);
                #pragma unroll
                for (int pt = 0; pt < 4; ++pt)
                    acc[nt][pt] = __builtin_amdgcn_mfma_f32_16x16x32_bf16(
                        a[pt], bf, acc[nt][pt], 0, 0, 0);
            }
        }
        // issue x loads: latency hides under bounce write + barrier + outb66 reads
        {
            const float* xbb = x + (size_t)b*CH*HW + p0;
            #pragma unroll
            for (int k = 0; k < 48; ++k)
                xvr[k] = xbb[(size_t)(48*w + k)*HW + px];
        }
        __syncthreads();
        // ---- P3: bounce oproj result (stride 66, bf16)
        #pragma unroll
        for (int nt = 0; nt < 3; ++nt){
            int ocl = w*48 + nt*16 + lo;
            #pragma unroll
            for (int pt = 0; pt < 4; ++pt)
                #pragma unroll
                for (int r = 0; r < 4; ++r)
                    outb66[ocl*66 + pt*16 + hi*4 + r] = (__bf16)acc[nt][pt][r];
        }
    }
    __syncthreads();

    // ---- P4: xr = x + bias + oproj (f32) ; LN2 stats
    unsigned xp[24];
    {
        float s = 0.f, s2 = 0.f;
        #pragma unroll
        for (int k = 0; k < 48; ++k){
            int c = 48*w + k;
            float v = xvr[k] + biaso[c] + (float)outb66[c*66 + px];
            xvr[k] = v; s += v; s2 += v*v;
        }
        redS[tid] = s; redQ[tid] = s2;
        __syncthreads();
        if (tid < 64){
            float S = redS[tid]+redS[tid+64]+redS[tid+128]+redS[tid+192];
            float Q = redQ[tid]+redQ[tid+64]+redQ[tid+128]+redQ[tid+192];
            float mean = S * (1.f/192.f);
            float var  = Q * (1.f/192.f) - mean*mean;
            mS[tid] = mean;
            rS[tid] = rsqrtf(var + 1e-6f);
        }
        __syncthreads();
        // ---- P5: LN2 -> frag-linear bf16 into h2s; pack xr to registers
        float mean = mS[px], rstd = rS[px];
        #pragma unroll
        for (int m = 0; m < 6; ++m){
            int c8 = 48*w + 8*m;
            int ks = c8 >> 5, hh = (c8 >> 3) & 3;
            bf16x8 pk;
            #pragma unroll
            for (int j = 0; j < 8; ++j){
                int c = c8 + j;
                pk[j] = (__bf16)((xvr[8*m + j] - mean) * rstd * lw[c] + lb[c]);
            }
            *(bf16x8*)(h2s + (((px>>4)*6 + ks)*64 + hh*16 + (px & 15))*8) = pk;
        }
        #pragma unroll
        for (int k2 = 0; k2 < 24; ++k2)
            xp[k2] = pack2bf(xvr[2*k2], xvr[2*k2+1]);
    }
    __syncthreads();

    // ---- P6: MLP loop (12 chunks x 64 hidden, dbuf tt, one barrier/chunk)
    f32x4 acc2[3][4];
    #pragma unroll
    for (int nt2 = 0; nt2 < 3; ++nt2)
        #pragma unroll
        for (int pt = 0; pt < 4; ++pt)
            acc2[nt2][pt] = (f32x4){0.f,0.f,0.f,0.f};

    int ks2c = w >> 1;
    int hi2c = 2*(w & 1) + (hi >> 1);
    int jbase = (hi & 1)*4;

    #pragma unroll 1
    for (int hc = 0; hc < 12; ++hc){
        int hb = hc*64;
        __bf16* ttw = (hc & 1) ? tt1 : tt0;
        f32x4 acc1[4];
        #pragma unroll
        for (int pt = 0; pt < 4; ++pt)
            acc1[pt] = (f32x4){0.f,0.f,0.f,0.f};
        #pragma unroll
        for (int ks = 0; ks < 6; ++ks){
            bf16x8 wf = *(const bf16x8*)
                (w1b + (size_t)(hb + w*16 + lo)*CH + ks*32 + hi*8);
            #pragma unroll
            for (int pt = 0; pt < 4; ++pt){
                bf16x8 a = *(const bf16x8*)(h2s + ((pt*6 + ks)*64 + lane)*8);
                acc1[pt] = __builtin_amdgcn_mfma_f32_16x16x32_bf16(
                    wf, a, acc1[pt], 0, 0, 0);
            }
        }
        {
            f32x4 bv4 = *(const f32x4*)(b1 + hb + w*16 + hi*4);
            #pragma unroll
            for (int pt = 0; pt < 4; ++pt){
                union { __bf16 h[4]; double d; } pk;
                #pragma unroll
                for (int r = 0; r < 4; ++r)
                    pk.h[r] = (__bf16)gelu_f(acc1[pt][r] + bv4[r]);
                *(double*)(ttw + ((pt*2 + ks2c)*64 + hi2c*16 + lo)*8 + jbase) = pk.d;
            }
        }
        __syncthreads();
        #pragma unroll
        for (int ks2 = 0; ks2 < 2; ++ks2){
            bf16x8 a2[4];
            #pragma unroll
            for (int pt = 0; pt < 4; ++pt)
                a2[pt] = *(const bf16x8*)(ttw + ((pt*2 + ks2)*64 + lane)*8);
            #pragma unroll
            for (int nt2 = 0; nt2 < 3; ++nt2){
                bf16x8 bf2 = *(const bf16x8*)
                    (w2b + (size_t)(w*48 + nt2*16 + lo)*HIDN + hb + ks2*32 + hi*8);
                #pragma unroll
                for (int pt = 0; pt < 4; ++pt)
                    acc2[nt2][pt] = __builtin_amdgcn_mfma_f32_16x16x32_bf16(
                        a2[pt], bf2, acc2[nt2][pt], 0, 0, 0);
            }
        }
    }
    __syncthreads();   // all tt/h2s reads complete before epilogue overwrites

    // ---- P7: epilogue in two 96-channel halves, f32 bounce (stride 68)
    float* iob = outp + (size_t)b*CH*HW + p0;
    #pragma unroll
    for (int half = 0; half < 2; ++half){
        if ((w >> 1) == half){
            #pragma unroll
            for (int nt2 = 0; nt2 < 3; ++nt2){
                int cl = (w & 1)*48 + nt2*16 + lo;     // local row 0..95
                #pragma unroll
                for (int pt = 0; pt < 4; ++pt)
                    #pragma unroll
                    for (int r = 0; r < 4; ++r)
                        outf[cl*68 + pt*16 + hi*4 + r] = acc2[nt2][pt][r];
            }
        }
        __syncthreads();
        if ((w >> 1) == half){
            #pragma unroll
            for (int k = 0; k < 48; ++k){
                int cl = (w & 1)*48 + k;
                union { unsigned u; float f; } vv;
                unsigned bits = (k & 1) ? (xp[k>>1] >> 16) : (xp[k>>1] & 0xffffu);
                vv.u = bits << 16;
                outf[cl*68 + px] += vv.f;
            }
        }
        __syncthreads();
        #pragma unroll
        for (int k = 0; k < 3; ++k){
            int V = tid + k*256;
            int cl = V >> 3, vg = V & 7;
            int c = half*96 + cl;
            f32x4 r0 = *(const f32x4*)(outf + cl*68 + vg*8);
            f32x4 r1 = *(const f32x4*)(outf + cl*68 + vg*8 + 4);
            float bv = b2[c];
            #pragma unroll
            for (int j = 0; j < 4; ++j){ r0[j] += bv; r1[j] += bv; }
            *(f32x4*)(iob + (size_t)c*HW + vg*8) = r0;
            *(f32x4*)(iob + (size_t)c*HW + vg*8 + 4) = r1;
        }
        __syncthreads();
    }
}

extern "C" void kernel_launch(void* const* d_in, const int* in_sizes, int n_in,
                              void* d_out, int out_size, void* d_ws, size_t ws_size,
                              hipStream_t stream) {
    const float* x    = (const float*)d_in[0];
    const float* ln1w = (const float*)d_in[1];
    const float* ln1b = (const float*)d_in[2];
    const float* ipw  = (const float*)d_in[3];
    const float* ipb  = (const float*)d_in[4];
    const float* dwk  = (const float*)d_in[5];
    const float* lek  = (const float*)d_in[6];
    const float* dlg  = (const float*)d_in[7];
    const float* mlg  = (const float*)d_in[8];
    const float* isc  = (const float*)d_in[9];
    const float* bnw  = (const float*)d_in[10];
    const float* bnb  = (const float*)d_in[11];
    const float* opw  = (const float*)d_in[12];
    const float* opb  = (const float*)d_in[13];
    const float* ln2w = (const float*)d_in[14];
    const float* ln2b = (const float*)d_in[15];
    const float* f1w  = (const float*)d_in[16];
    const float* f1b  = (const float*)d_in[17];
    const float* f2w  = (const float*)d_in[18];
    const float* f2b  = (const float*)d_in[19];

    float* out = (float*)d_out;
    __bf16* bufP = (__bf16*)d_ws;                      // proj bf16
    __bf16* bufG = bufP + (size_t)NELEM;               // gate bf16
    __bf16* bufM = bufG + (size_t)NELEM;               // mixed bf16
    float* part = (float*)(bufM + (size_t)NELEM);
    __bf16* ipwb = (__bf16*)(part + 2*NB*CH);
    __bf16* opwb = ipwb + (size_t)2*CH*CH;
    __bf16* w1b  = opwb + (size_t)CH*CH;
    __bf16* w2b  = w1b  + (size_t)HIDN*CH;

    const int ncvt = 2*CH*CH + CH*CH + 2*HIDN*CH;
    k_cvt_all<<<(ncvt + 255)/256, 256, 0, stream>>>(ipw, opw, f1w, f2w, ipwb);

    k_ln_inproj<<<1024, 256, 0, stream>>>(x, ln1w, ln1b, ipwb, ipb, bufP, bufG);
    k_spatial  <<<NB*CH, 256, 0, stream>>>(bufP, bufG, dwk, lek, dlg, mlg, isc, bufM, part);
    k_tail2    <<<1024, 256, 0, stream>>>(bufM, part, bnw, bnb, opwb, opb, x, ln2w, ln2b,
                                          w1b, f1b, w2b, f2b, out);
}

// Round 23
// 199.850 us; speedup vs baseline: 1.0261x; 1.0261x over previous
//
#include <hip/hip_runtime.h>
#include <math.h>

#define CH 192
#define HW 4096
#define NB 16
#define NELEM (NB*CH*HW)
#define HIDN 768

typedef __bf16 bf16x8 __attribute__((ext_vector_type(8)));
typedef float  f32x4  __attribute__((ext_vector_type(4)));
typedef unsigned uint4v __attribute__((ext_vector_type(4)));

__device__ __forceinline__ float gelu_f(float v){
    return v / (1.0f + __expf(-1.702f*v));
}
__device__ __forceinline__ float sigmoid_f(float v){
    return 1.0f / (1.0f + __expf(-v));
}
__device__ __forceinline__ unsigned pack2bf(float a, float b){
    union { __bf16 h[2]; unsigned u; } v;
    v.h[0] = (__bf16)a; v.h[1] = (__bf16)b; return v.u;
}

// ---------------- K0: f32 -> bf16 weight conversion, all four matrices in one launch
__global__ __launch_bounds__(256) void k_cvt_all(
    const float* __restrict__ a0, const float* __restrict__ a1,
    const float* __restrict__ a2, const float* __restrict__ a3,
    __bf16* __restrict__ o)
{
    const int n0 = 2*CH*CH, n1 = CH*CH, n2 = HIDN*CH, n3 = CH*HIDN;
    int i = blockIdx.x*256 + threadIdx.x;
    if (i < n0) o[i] = (__bf16)a0[i];
    else if (i < n0+n1) o[i] = (__bf16)a1[i-n0];
    else if (i < n0+n1+n2) o[i] = (__bf16)a2[i-n0-n1];
    else if (i < n0+n1+n2+n3) o[i] = (__bf16)a3[i-n0-n1-n2];
}

// ---------------- K1: LN1 + in_proj (192->384) via bf16 MFMA -> bf16 proj / sigmoid gate
__global__ __launch_bounds__(256, 4) void k_ln_inproj(
    const float* __restrict__ x, const float* __restrict__ lw, const float* __restrict__ lb,
    const __bf16* __restrict__ Wb, const float* __restrict__ bias,
    __bf16* __restrict__ proj, __bf16* __restrict__ gate)
{
    __shared__ __align__(16) unsigned char smem[33792];
    __bf16* h2s = (__bf16*)smem;                       // 192*64 frag-linear (24576B)
    float* redS = (float*)(smem + 24576);              // LN scratch (dead post-MFMA)
    float* redQ = (float*)(smem + 25600);
    float* mS   = (float*)(smem + 26624);
    float* rS   = (float*)(smem + 26880);
    __bf16* outb = (__bf16*)(smem + 24576);            // 64ch x 72 bounce (9216B)

    int tid = threadIdx.x;
    int lane = tid & 63;
    int w = tid >> 6;
    int lo = lane & 15, hi = lane >> 4;
    int bid = blockIdx.x;
    int b = bid >> 6;
    int p0 = (bid & 63) << 6;
    const float* xb = x + (size_t)b*CH*HW + p0;
    int px = lane;

    float xv[48];
    float s = 0.f, s2 = 0.f;
    #pragma unroll
    for (int k = 0; k < 48; ++k){
        float v = xb[(size_t)(48*w + k)*HW + px];
        xv[k] = v; s += v; s2 += v*v;
    }
    redS[tid] = s; redQ[tid] = s2;
    __syncthreads();
    if (tid < 64){
        float S = redS[tid]+redS[tid+64]+redS[tid+128]+redS[tid+192];
        float Q = redQ[tid]+redQ[tid+64]+redQ[tid+128]+redQ[tid+192];
        float mean = S * (1.f/192.f);
        float var  = Q * (1.f/192.f) - mean*mean;
        mS[tid] = mean;
        rS[tid] = rsqrtf(var + 1e-6f);
    }
    __syncthreads();
    {
        float mean = mS[px], rstd = rS[px];
        #pragma unroll
        for (int m = 0; m < 6; ++m){
            int c8 = 48*w + 8*m;
            int ks = c8 >> 5, hh = (c8 >> 3) & 3;
            bf16x8 pk;
            #pragma unroll
            for (int j = 0; j < 8; ++j){
                int c = c8 + j;
                pk[j] = (__bf16)((xv[8*m + j] - mean) * rstd * lw[c] + lb[c]);
            }
            *(bf16x8*)(h2s + (((px>>4)*6 + ks)*64 + hh*16 + (px & 15))*8) = pk;
        }
    }
    __syncthreads();

    #pragma unroll
    for (int g = 0; g < 2; ++g){
        f32x4 acc[3][4];
        #pragma unroll
        for (int nt = 0; nt < 3; ++nt)
            #pragma unroll
            for (int pt = 0; pt < 4; ++pt)
                acc[nt][pt] = (f32x4){0.f,0.f,0.f,0.f};
        #pragma unroll
        for (int ks = 0; ks < 6; ++ks){
            bf16x8 a[4];
            #pragma unroll
            for (int pt = 0; pt < 4; ++pt)
                a[pt] = *(const bf16x8*)(h2s + ((pt*6 + ks)*64 + lane)*8);
            #pragma unroll
            for (int nt = 0; nt < 3; ++nt){
                bf16x8 bf = *(const bf16x8*)
                    (Wb + (size_t)(g*192 + w*48 + nt*16 + lo)*CH + ks*32 + hi*8);
                #pragma unroll
                for (int pt = 0; pt < 4; ++pt)
                    acc[nt][pt] = __builtin_amdgcn_mfma_f32_16x16x32_bf16(
                        a[pt], bf, acc[nt][pt], 0, 0, 0);
            }
        }
        __bf16* dst = (g == 0) ? proj : gate;
        #pragma unroll
        for (int nt = 0; nt < 3; ++nt){
            __syncthreads();
            int oc = w*48 + nt*16 + lo;
            float bv = bias[g*CH + oc];
            int cc = w*16 + lo;
            #pragma unroll
            for (int pt = 0; pt < 4; ++pt)
                #pragma unroll
                for (int r = 0; r < 4; ++r){
                    float v = acc[nt][pt][r] + bv;
                    if (g == 1) v = sigmoid_f(v);
                    outb[cc*72 + pt*16 + hi*4 + r] = (__bf16)v;
                }
            __syncthreads();
            #pragma unroll
            for (int k = 0; k < 2; ++k){
                int i = tid + k*256;
                int c2 = i >> 3, vg = i & 7;
                int c = (c2 >> 4)*48 + nt*16 + (c2 & 15);
                bf16x8 o8 = *(const bf16x8*)(outb + c2*72 + vg*8);
                *(bf16x8*)(dst + (size_t)(b*CH + c)*HW + p0 + vg*8) = o8;
            }
        }
        __syncthreads();
    }
}

// ---------------- K2: fused spatial: dwconv3 + 4-dir scans + local conv3 + gate + BN partials
__global__ __launch_bounds__(256, 4) void k_spatial(
    const __bf16* __restrict__ proj, const __bf16* __restrict__ gate,
    const float* __restrict__ dwk, const float* __restrict__ lek,
    const float* __restrict__ dl, const float* __restrict__ ml, const float* __restrict__ il,
    __bf16* __restrict__ mixed, float* __restrict__ part)
{
    __shared__ float t[66*67];
    __shared__ __bf16 r[64*65];
    __shared__ __bf16 r2[64*65];
    __shared__ float rs[256], rq[256];
    int tid = threadIdx.x;
    int lane = tid & 63;
    int w = tid >> 6;
    int bc = blockIdx.x;
    int c = bc % CH;
    const __bf16* pp = proj + (size_t)bc*HW;

    for (int i = tid; i < 66*67; i += 256) t[i] = 0.f;
    float d[4], e[4], m[4];
    {
        float lg[4], mx = -1e30f;
        #pragma unroll
        for (int k = 0; k < 4; ++k){ lg[k] = ml[k*CH + c]; mx = fmaxf(mx, lg[k]); }
        float se = 0.f;
        #pragma unroll
        for (int k = 0; k < 4; ++k){ lg[k] = __expf(lg[k]-mx); se += lg[k]; }
        #pragma unroll
        for (int k = 0; k < 4; ++k){
            m[k] = lg[k] / se;
            float dd = sigmoid_f(dl[k*CH + c]);
            dd = fminf(fmaxf(dd, 0.05f), 0.995f);
            d[k] = dd;
            e[k] = (1.0f - dd) * (1.0f + tanhf(il[k*CH + c]));
        }
    }
    __syncthreads();
    #pragma unroll
    for (int k = 0; k < 2; ++k){
        int i = tid + k*256;
        int y = i >> 3, vg = i & 7;
        bf16x8 p8 = *(const bf16x8*)(pp + y*64 + vg*8);
        #pragma unroll
        for (int j = 0; j < 8; ++j)
            t[(y+1)*67 + vg*8 + j + 1] = (float)p8[j];
    }
    __syncthreads();
    float kk[9];
    #pragma unroll
    for (int j = 0; j < 9; ++j) kk[j] = dwk[c*9 + j];
    float dw[16];
    #pragma unroll
    for (int j = 0; j < 16; ++j){
        int i = tid + j*256;
        int y = i >> 6, xx = i & 63;
        float sv = 0.f;
        #pragma unroll
        for (int dy = 0; dy < 3; ++dy)
            #pragma unroll
            for (int dx = 0; dx < 3; ++dx)
                sv = fmaf(kk[dy*3+dx], t[(y+dy)*67 + xx + dx], sv);
        dw[j] = sv;
    }
    __syncthreads();
    #pragma unroll
    for (int j = 0; j < 16; ++j){
        int i = tid + j*256;
        t[((i>>6)+1)*67 + (i & 63) + 1] = dw[j];
    }
    __syncthreads();
    if (w == 0){
        int y = lane; float s = 0.f;
        for (int xx = 0; xx < 64; ++xx){
            s = fmaf(d[0], s, e[0]*t[(y+1)*67 + xx + 1]);
            r[y*65 + xx] = (__bf16)(m[0]*s);
        }
    } else if (w == 1){
        int xx = lane; float s = 0.f;
        for (int y = 0; y < 64; ++y){
            s = fmaf(d[2], s, e[2]*t[(y+1)*67 + xx + 1]);
            r2[y*65 + xx] = (__bf16)(m[2]*s);
        }
    }
    __syncthreads();
    if (w == 2){
        int y = lane; float s = 0.f;
        for (int xx = 63; xx >= 0; --xx){
            s = fmaf(d[1], s, e[1]*t[(y+1)*67 + xx + 1]);
            r[y*65 + xx] = (__bf16)((float)r[y*65 + xx] + m[1]*s);
        }
    } else if (w == 3){
        int xx = lane; float s = 0.f;
        for (int y = 63; y >= 0; --y){
            s = fmaf(d[3], s, e[3]*t[(y+1)*67 + xx + 1]);
            r2[y*65 + xx] = (__bf16)((float)r2[y*65 + xx] + m[3]*s);
        }
    }
    __syncthreads();
    float lk[9];
    #pragma unroll
    for (int j = 0; j < 9; ++j) lk[j] = lek[c*9 + j];
    const __bf16* gp = gate + (size_t)bc*HW;
    __bf16* mp = mixed + (size_t)bc*HW;
    float s1 = 0.f, s2 = 0.f;
    #pragma unroll
    for (int k = 0; k < 2; ++k){
        int i = tid + k*256;
        int y = i >> 3, vg = i & 7;
        bf16x8 g8 = *(const bf16x8*)(gp + y*64 + vg*8);
        bf16x8 m8;
        #pragma unroll
        for (int j = 0; j < 8; ++j){
            int xx = vg*8 + j;
            float sv = 0.f;
            #pragma unroll
            for (int dy = 0; dy < 3; ++dy)
                #pragma unroll
                for (int dx = 0; dx < 3; ++dx)
                    sv = fmaf(lk[dy*3+dx], t[(y+dy)*67 + xx + dx], sv);
            float mv = ((float)r[y*65 + xx] + (float)r2[y*65 + xx] + sv) * (float)g8[j];
            m8[j] = (__bf16)mv;
            s1 += mv; s2 += mv*mv;
        }
        *(bf16x8*)(mp + y*64 + vg*8) = m8;
    }
    rs[tid] = s1; rq[tid] = s2;
    __syncthreads();
    for (int off = 128; off > 0; off >>= 1){
        if (tid < off){ rs[tid] += rs[tid+off]; rq[tid] += rq[tid+off]; }
        __syncthreads();
    }
    if (tid == 0){ part[bc] = rs[0]; part[NB*CH + bc] = rq[0]; }
}

// ---------------- K3: FUSED tail: BN-finalize (per-block, from part) + BN+GELU + out_proj
// + residual + LN2 (LDS-resident) + fc1 + GELU + fc2 + final write.
// xr held as 24 packed-bf16 VGPRs across the MLP loop. LDS 40960 -> 4 blocks/CU.
__global__ __launch_bounds__(256, 4) void k_tail2(
    const __bf16* __restrict__ mixed,
    const float* __restrict__ part, const float* __restrict__ bnw, const float* __restrict__ bnb,
    const __bf16* __restrict__ Wo, const float* __restrict__ biaso,
    const float* __restrict__ x,
    const float* __restrict__ lw, const float* __restrict__ lb,
    const __bf16* __restrict__ w1b, const float* __restrict__ b1,
    const __bf16* __restrict__ w2b, const float* __restrict__ b2,
    float* __restrict__ outp)
{
    __shared__ __align__(16) unsigned char smem[40960];
    __bf16* h2s = (__bf16*)smem;                    // 24576B act frags (persistent in MLP)
    __bf16* tt0 = (__bf16*)(smem + 24576);          // 8192B fc1-out frags, buffer 0
    __bf16* tt1 = (__bf16*)(smem + 32768);          // 8192B fc1-out frags, buffer 1
    __bf16* outb66 = (__bf16*)smem;                 // 192*66 bf16 oproj bounce (25344B)
    float* redS = (float*)(smem + 25600);           // LN scratch in tt region (tt dead)
    float* redQ = (float*)(smem + 26624);
    float* mS   = (float*)(smem + 27648);
    float* rS   = (float*)(smem + 27904);
    float* bnpl = (float*)(smem + 28160);           // 2*192 f32 BN scale/shift (1536B)
    float* outf = (float*)smem;                     // 96*68 f32 epilogue bounce (26112B)

    int tid = threadIdx.x;
    int lane = tid & 63;
    int w = tid >> 6;
    int lo = lane & 15, hi = lane >> 4;
    int bid = blockIdx.x;
    int b = bid >> 6;
    int p0 = (bid & 63) << 6;
    int px = lane;
    const __bf16* mb = mixed + (size_t)b*CH*HW + p0;

    // ---- P0: BN finalize (redundant per block; part is L2-hot, 16 adds/thread)
    if (tid < CH){
        float S = 0.f, Q = 0.f;
        #pragma unroll
        for (int bb2 = 0; bb2 < NB; ++bb2){
            S += part[bb2*CH + tid];
            Q += part[NB*CH + bb2*CH + tid];
        }
        float mean = S * (1.f/65536.f);
        float var  = Q * (1.f/65536.f) - mean*mean;
        float sc = bnw[tid] * rsqrtf(var + 1e-5f);
        bnpl[tid] = sc;
        bnpl[CH + tid] = bnb[tid] - mean * sc;
    }
    __syncthreads();

    // ---- P1: BN + GELU(mixed) -> frag-linear bf16 (vectorized reads)
    #pragma unroll
    for (int k = 0; k < 6; ++k){
        int V = tid + k*256;
        int c = V >> 3, vg = V & 7;
        bf16x8 m8 = *(const bf16x8*)(mb + (size_t)c*HW + vg*8);
        int ks = c >> 5, hh = (c >> 3) & 3, j2 = c & 7;
        float sc_ = bnpl[c], sh_ = bnpl[CH + c];
        #pragma unroll
        for (int j = 0; j < 8; ++j){
            int p2 = vg*8 + j;
            float v = gelu_f(fmaf((float)m8[j], sc_, sh_));
            h2s[((((p2>>4)*6 + ks) << 6) + hh*16 + (p2 & 15))*8 + j2] = (__bf16)v;
        }
    }
    __syncthreads();

    // ---- P2: out_proj MFMA
    {
        f32x4 acc[3][4];
        #pragma unroll
        for (int nt = 0; nt < 3; ++nt)
            #pragma unroll
            for (int pt = 0; pt < 4; ++pt)
                acc[nt][pt] = (f32x4){0.f,0.f,0.f,0.f};
        #pragma unroll
        for (int ks = 0; ks < 6; ++ks){
            bf16x8 a[4];
            #pragma unroll
            for (int pt = 0; pt < 4; ++pt)
                a[pt] = *(const bf16x8*)(h2s + ((pt*6 + ks)*64 + lane)*8);
            #pragma unroll
            for (int nt = 0; nt < 3; ++nt){
                bf16x8 bf = *(const bf16x8*)
                    (Wo + (size_t)(w*48 + nt*16 + lo)*CH + ks*32 + hi*8);
                #pragma unroll
                for (int pt = 0; pt < 4; ++pt)
                    acc[nt][pt] = __builtin_amdgcn_mfma_f32_16x16x32_bf16(
                        a[pt], bf, acc[nt][pt], 0, 0, 0);
            }
        }
        __syncthreads();
        // ---- P3: bounce oproj result (stride 66, bf16)
        #pragma unroll
        for (int nt = 0; nt < 3; ++nt){
            int ocl = w*48 + nt*16 + lo;
            #pragma unroll
            for (int pt = 0; pt < 4; ++pt)
                #pragma unroll
                for (int r = 0; r < 4; ++r)
                    outb66[ocl*66 + pt*16 + hi*4 + r] = (__bf16)acc[nt][pt][r];
        }
    }
    __syncthreads();

    // ---- P4: xr = x + bias + oproj (f32) ; LN2 stats
    unsigned xp[24];
    {
        const float* xbb = x + (size_t)b*CH*HW + p0;
        float xv[48];
        float s = 0.f, s2 = 0.f;
        #pragma unroll
        for (int k = 0; k < 48; ++k){
            int c = 48*w + k;
            float v = xbb[(size_t)c*HW + px] + biaso[c] + (float)outb66[c*66 + px];
            xv[k] = v; s += v; s2 += v*v;
        }
        redS[tid] = s; redQ[tid] = s2;
        __syncthreads();
        if (tid < 64){
            float S = redS[tid]+redS[tid+64]+redS[tid+128]+redS[tid+192];
            float Q = redQ[tid]+redQ[tid+64]+redQ[tid+128]+redQ[tid+192];
            float mean = S * (1.f/192.f);
            float var  = Q * (1.f/192.f) - mean*mean;
            mS[tid] = mean;
            rS[tid] = rsqrtf(var + 1e-6f);
        }
        __syncthreads();
        // ---- P5: LN2 -> frag-linear bf16 into h2s; pack xr to registers
        float mean = mS[px], rstd = rS[px];
        #pragma unroll
        for (int m = 0; m < 6; ++m){
            int c8 = 48*w + 8*m;
            int ks = c8 >> 5, hh = (c8 >> 3) & 3;
            bf16x8 pk;
            #pragma unroll
            for (int j = 0; j < 8; ++j){
                int c = c8 + j;
                pk[j] = (__bf16)((xv[8*m + j] - mean) * rstd * lw[c] + lb[c]);
            }
            *(bf16x8*)(h2s + (((px>>4)*6 + ks)*64 + hh*16 + (px & 15))*8) = pk;
        }
        #pragma unroll
        for (int k2 = 0; k2 < 24; ++k2)
            xp[k2] = pack2bf(xv[2*k2], xv[2*k2+1]);
    }
    __syncthreads();

    // ---- P6: MLP loop (12 chunks x 64 hidden, dbuf tt, one barrier/chunk)
    f32x4 acc2[3][4];
    #pragma unroll
    for (int nt2 = 0; nt2 < 3; ++nt2)
        #pragma unroll
        for (int pt = 0; pt < 4; ++pt)
            acc2[nt2][pt] = (f32x4){0.f,0.f,0.f,0.f};

    int ks2c = w >> 1;
    int hi2c = 2*(w & 1) + (hi >> 1);
    int jbase = (hi & 1)*4;

    #pragma unroll 1
    for (int hc = 0; hc < 12; ++hc){
        int hb = hc*64;
        __bf16* ttw = (hc & 1) ? tt1 : tt0;
        f32x4 acc1[4];
        #pragma unroll
        for (int pt = 0; pt < 4; ++pt)
            acc1[pt] = (f32x4){0.f,0.f,0.f,0.f};
        #pragma unroll
        for (int ks = 0; ks < 6; ++ks){
            bf16x8 wf = *(const bf16x8*)
                (w1b + (size_t)(hb + w*16 + lo)*CH + ks*32 + hi*8);
            #pragma unroll
            for (int pt = 0; pt < 4; ++pt){
                bf16x8 a = *(const bf16x8*)(h2s + ((pt*6 + ks)*64 + lane)*8);
                acc1[pt] = __builtin_amdgcn_mfma_f32_16x16x32_bf16(
                    wf, a, acc1[pt], 0, 0, 0);
            }
        }
        {
            f32x4 bv4 = *(const f32x4*)(b1 + hb + w*16 + hi*4);
            #pragma unroll
            for (int pt = 0; pt < 4; ++pt){
                union { __bf16 h[4]; double d; } pk;
                #pragma unroll
                for (int r = 0; r < 4; ++r)
                    pk.h[r] = (__bf16)gelu_f(acc1[pt][r] + bv4[r]);
                *(double*)(ttw + ((pt*2 + ks2c)*64 + hi2c*16 + lo)*8 + jbase) = pk.d;
            }
        }
        __syncthreads();
        #pragma unroll
        for (int ks2 = 0; ks2 < 2; ++ks2){
            bf16x8 a2[4];
            #pragma unroll
            for (int pt = 0; pt < 4; ++pt)
                a2[pt] = *(const bf16x8*)(ttw + ((pt*2 + ks2)*64 + lane)*8);
            #pragma unroll
            for (int nt2 = 0; nt2 < 3; ++nt2){
                bf16x8 bf2 = *(const bf16x8*)
                    (w2b + (size_t)(w*48 + nt2*16 + lo)*HIDN + hb + ks2*32 + hi*8);
                #pragma unroll
                for (int pt = 0; pt < 4; ++pt)
                    acc2[nt2][pt] = __builtin_amdgcn_mfma_f32_16x16x32_bf16(
                        a2[pt], bf2, acc2[nt2][pt], 0, 0, 0);
            }
        }
    }
    __syncthreads();   // all tt/h2s reads complete before epilogue overwrites

    // ---- P7: epilogue in two 96-channel halves, f32 bounce (stride 68)
    float* iob = outp + (size_t)b*CH*HW + p0;
    #pragma unroll
    for (int half = 0; half < 2; ++half){
        if ((w >> 1) == half){
            #pragma unroll
            for (int nt2 = 0; nt2 < 3; ++nt2){
                int cl = (w & 1)*48 + nt2*16 + lo;     // local row 0..95
                #pragma unroll
                for (int pt = 0; pt < 4; ++pt)
                    #pragma unroll
                    for (int r = 0; r < 4; ++r)
                        outf[cl*68 + pt*16 + hi*4 + r] = acc2[nt2][pt][r];
            }
        }
        __syncthreads();
        if ((w >> 1) == half){
            #pragma unroll
            for (int k = 0; k < 48; ++k){
                int cl = (w & 1)*48 + k;
                union { unsigned u; float f; } vv;
                unsigned bits = (k & 1) ? (xp[k>>1] >> 16) : (xp[k>>1] & 0xffffu);
                vv.u = bits << 16;
                outf[cl*68 + px] += vv.f;
            }
        }
        __syncthreads();
        #pragma unroll
        for (int k = 0; k < 3; ++k){
            int V = tid + k*256;
            int cl = V >> 3, vg = V & 7;
            int c = half*96 + cl;
            f32x4 r0 = *(const f32x4*)(outf + cl*68 + vg*8);
            f32x4 r1 = *(const f32x4*)(outf + cl*68 + vg*8 + 4);
            float bv = b2[c];
            #pragma unroll
            for (int j = 0; j < 4; ++j){ r0[j] += bv; r1[j] += bv; }
            *(f32x4*)(iob + (size_t)c*HW + vg*8) = r0;
            *(f32x4*)(iob + (size_t)c*HW + vg*8 + 4) = r1;
        }
        __syncthreads();
    }
}

extern "C" void kernel_launch(void* const* d_in, const int* in_sizes, int n_in,
                              void* d_out, int out_size, void* d_ws, size_t ws_size,
                              hipStream_t stream) {
    const float* x    = (const float*)d_in[0];
    const float* ln1w = (const float*)d_in[1];
    const float* ln1b = (const float*)d_in[2];
    const float* ipw  = (const float*)d_in[3];
    const float* ipb  = (const float*)d_in[4];
    const float* dwk  = (const float*)d_in[5];
    const float* lek  = (const float*)d_in[6];
    const float* dlg  = (const float*)d_in[7];
    const float* mlg  = (const float*)d_in[8];
    const float* isc  = (const float*)d_in[9];
    const float* bnw  = (const float*)d_in[10];
    const float* bnb  = (const float*)d_in[11];
    const float* opw  = (const float*)d_in[12];
    const float* opb  = (const float*)d_in[13];
    const float* ln2w = (const float*)d_in[14];
    const float* ln2b = (const float*)d_in[15];
    const float* f1w  = (const float*)d_in[16];
    const float* f1b  = (const float*)d_in[17];
    const float* f2w  = (const float*)d_in[18];
    const float* f2b  = (const float*)d_in[19];

    float* out = (float*)d_out;
    __bf16* bufP = (__bf16*)d_ws;                      // proj bf16
    __bf16* bufG = bufP + (size_t)NELEM;               // gate bf16
    __bf16* bufM = bufG + (size_t)NELEM;               // mixed bf16
    float* part = (float*)(bufM + (size_t)NELEM);
    __bf16* ipwb = (__bf16*)(part + 2*NB*CH);
    __bf16* opwb = ipwb + (size_t)2*CH*CH;
    __bf16* w1b  = opwb + (size_t)CH*CH;
    __bf16* w2b  = w1b  + (size_t)HIDN*CH;

    const int ncvt = 2*CH*CH + CH*CH + 2*HIDN*CH;
    k_cvt_all<<<(ncvt + 255)/256, 256, 0, stream>>>(ipw, opw, f1w, f2w, ipwb);

    k_ln_inproj<<<1024, 256, 0, stream>>>(x, ln1w, ln1b, ipwb, ipb, bufP, bufG);
    k_spatial  <<<NB*CH, 256, 0, stream>>>(bufP, bufG, dwk, lek, dlg, mlg, isc, bufM, part);
    k_tail2    <<<1024, 256, 0, stream>>>(bufM, part, bnw, bnb, opwb, opb, x, ln2w, ln2b,
                                          w1b, f1b, w2b, f2b, out);
}